// Round 8
// baseline (5028.437 us; speedup 1.0000x reference)
//
#include <hip/hip_runtime.h>
#include <hip/hip_bf16.h>

#define SEQL  2048
#define IND   256
#define MEMD  512
#define G4    2048   // 4*MEMD gate rows
#define NWGS  8      // workgroups per sequence (fat: 1024 threads each)
#define VOCABN 100000

typedef __attribute__((ext_vector_type(4))) unsigned uintx4;
typedef __attribute__((ext_vector_type(2))) _Float16 half2v;

__device__ __forceinline__ unsigned short f2h_bits(float f) {
  _Float16 h = (_Float16)f;
  return __builtin_bit_cast(unsigned short, h);
}
__device__ __forceinline__ float h2f(unsigned bits) {
  return (float)__builtin_bit_cast(_Float16, (unsigned short)(bits & 0xffffu));
}

// DPP xor-fold add within 16-lane rows. CTRL: 0xB1=xor1, 0x4E=xor2,
// 0x141=row_half_mirror(xor7), 0x140=row_mirror(xor15).
template <int CTRL>
__device__ __forceinline__ float dpp_fold_add(float v) {
  int x = __builtin_amdgcn_update_dpp(0, __float_as_int(v), CTRL, 0xf, 0xf, true);
  return v + __int_as_float(x);
}

// ---------- init: zero the h publication buffer ----------
// hbuf layout: [seq][parity][512] u32 words, word = (epoch<<16) | f16(h)
__global__ void init_k(unsigned* __restrict__ hbuf) {
  int i = blockIdx.x * blockDim.x + threadIdx.x;
  if (i < 2 * 2 * MEMD) hbuf[i] = 0u;   // epoch 0, h = 0
}

// ---------- xp GEMM: xp[s][t][perm(n)] = emb[ids[t]] . W_ih[n] + b ----------
// Output layout per (s,t): pos = w*256 + hd*4 + gate  (ushort4 per (w,hd)), f16
__global__ __launch_bounds__(256) void xp_gemm(
    const int* __restrict__ lin, const int* __restrict__ rin,
    const float* __restrict__ emb, const float* __restrict__ W_ih,
    const float* __restrict__ b_ih, const float* __restrict__ b_hh,
    unsigned short* __restrict__ xp) {
  __shared__ float As[64][68];
  __shared__ float Bs[64][68];
  const int s = blockIdx.z;
  const int* ids = (s == 0) ? lin : rin;
  const int t0 = blockIdx.x * 64;
  const int n0 = blockIdx.y * 64;
  const int tid = threadIdx.x;
  const int tx = tid & 15, ty = tid >> 4;

  float acc[4][4];
#pragma unroll
  for (int i = 0; i < 4; ++i)
#pragma unroll
    for (int j = 0; j < 4; ++j) acc[i][j] = 0.f;

  for (int kc = 0; kc < IND; kc += 64) {
#pragma unroll
    for (int j = 0; j < 4; ++j) {
      int fi  = tid + 256 * j;       // 0..1023 float4 slots
      int row = fi >> 4;             // 0..63
      int c4  = fi & 15;             // float4 index within 64 k
      int id  = ids[t0 + row];
      id = max(0, min(id, VOCABN - 1));
      const float4 va = *(const float4*)(emb + (size_t)id * IND + kc + c4 * 4);
      As[c4 * 4 + 0][row] = va.x; As[c4 * 4 + 1][row] = va.y;
      As[c4 * 4 + 2][row] = va.z; As[c4 * 4 + 3][row] = va.w;
      const float4 vb = *(const float4*)(W_ih + (size_t)(n0 + row) * IND + kc + c4 * 4);
      Bs[c4 * 4 + 0][row] = vb.x; Bs[c4 * 4 + 1][row] = vb.y;
      Bs[c4 * 4 + 2][row] = vb.z; Bs[c4 * 4 + 3][row] = vb.w;
    }
    __syncthreads();
#pragma unroll 8
    for (int k = 0; k < 64; ++k) {
      const float4 a = *(const float4*)&As[k][tx * 4];
      const float4 b = *(const float4*)&Bs[k][ty * 4];
      acc[0][0] = fmaf(a.x, b.x, acc[0][0]); acc[0][1] = fmaf(a.x, b.y, acc[0][1]);
      acc[0][2] = fmaf(a.x, b.z, acc[0][2]); acc[0][3] = fmaf(a.x, b.w, acc[0][3]);
      acc[1][0] = fmaf(a.y, b.x, acc[1][0]); acc[1][1] = fmaf(a.y, b.y, acc[1][1]);
      acc[1][2] = fmaf(a.y, b.z, acc[1][2]); acc[1][3] = fmaf(a.y, b.w, acc[1][3]);
      acc[2][0] = fmaf(a.z, b.x, acc[2][0]); acc[2][1] = fmaf(a.z, b.y, acc[2][1]);
      acc[2][2] = fmaf(a.z, b.z, acc[2][2]); acc[2][3] = fmaf(a.z, b.w, acc[2][3]);
      acc[3][0] = fmaf(a.w, b.x, acc[3][0]); acc[3][1] = fmaf(a.w, b.y, acc[3][1]);
      acc[3][2] = fmaf(a.w, b.z, acc[3][2]); acc[3][3] = fmaf(a.w, b.w, acc[3][3]);
    }
    __syncthreads();
  }
#pragma unroll
  for (int ri = 0; ri < 4; ++ri) {
#pragma unroll
    for (int bj = 0; bj < 4; ++bj) {
      int t = t0 + tx * 4 + ri;
      int n = n0 + ty * 4 + bj;
      float v = acc[ri][bj] + b_ih[n] + b_hh[n];
      int w = (n & 511) >> 6;     // owning WG (8 per sequence)
      int gate = n >> 9;          // 0..3 (i,f,g,o)
      int hd = n & 63;            // local h dim within WG
      int pos = w * 256 + hd * 4 + gate;
      xp[((size_t)s * SEQL + t) * G4 + pos] = f2h_bits(v);
    }
  }
}

// ---------- persistent recurrent kernel ----------
// 16 blocks x 1024 threads. block -> (seq = blk&1, w = blk>>1, w in 0..7).
// Each WG owns 64 h-dims. Gate-major: thread (cg=tid&15, rg=tid>>4 in 0..63)
// computes the 4 GATES of h-dim rg over k-chunk cg via v_dot2_f32_f16.
// DPP xor-fold -> all 16 lanes hold the 4 gate sums -> in-register gate math,
// single barrier. Waves 0,1 poll (one dwordx4 sc0 sc1 per lane per cadence).
// COHERENCE: poll loads MUST carry sc0 sc1 (agent scope) — sc0 alone can hit
// a stale clean line in this XCD's L2 forever (R6 livelock).
__global__ __launch_bounds__(1024, 1) void lstm_rec(
    const float* __restrict__ W_hh,
    const unsigned short* __restrict__ xp,
    unsigned* __restrict__ hbuf) {
  __shared__ unsigned hlds[16 * 20];  // 16 chunks x 16 half2-words, stride 20
  const int blk = blockIdx.x;
  const int s = blk & 1;
  const int w = blk >> 1;          // 0..7
  const int tid = threadIdx.x;
  const int lane = tid & 63;
  const int wv = tid >> 6;         // wave id 0..15
  const int cg = tid & 15;         // k chunk group (32 k each)
  const int rg = tid >> 4;         // h dim owned (0..63); wave wv owns rgs 4wv..4wv+3

  // W slice, gate-major, f16-packed: wreg[g][p] = {W[row][cg*32+2p], W[row][cg*32+2p+1]}
  half2v wreg[4][16];
#pragma unroll
  for (int g = 0; g < 4; ++g) {
    const float* src = W_hh + ((size_t)g * MEMD + w * 64 + rg) * MEMD + cg * 32;
#pragma unroll
    for (int q = 0; q < 8; ++q) {
      const float4 v = *(const float4*)(src + q * 4);
      half2v p0; p0.x = (_Float16)v.x; p0.y = (_Float16)v.y;
      half2v p1; p1.x = (_Float16)v.z; p1.y = (_Float16)v.w;
      wreg[g][q * 2 + 0] = p0;
      wreg[g][q * 2 + 1] = p1;
    }
  }

  unsigned* hbase = hbuf + s * (2 * MEMD);
  // this thread's 4 gate biases: xp[s][t][w*256 + rg*4 + 0..3]
  const unsigned short* xq0 = xp + (size_t)s * SEQL * G4 + w * 256 + rg * 4;
  float cst = 0.f;                 // cell state for h-dim rg (redundant in 16 lanes)

  ushort4 xg_cur = *(const ushort4*)xq0;   // t = 0

  const int pidx = wv * 64 + lane; // poller word-group index (waves 0,1 -> 0..127)

  for (int t = 0; t < SEQL; ++t) {
    // prefetch next step's gate biases (independent of h -> hides L2 latency)
    ushort4 xg_next;
    {
      int tn = (t + 1 < SEQL) ? t + 1 : t;
      xg_next = *(const ushort4*)(xq0 + (size_t)tn * G4);
    }

    // ---- waves 0,1: poll h_t (epoch == t); lane owns words 4p..4p+3 ----
    if (wv < 2) {
      const unsigned* hr = hbase + (t & 1) * MEMD + 4 * pidx;
      unsigned long long a0 = (unsigned long long)hr;
      uintx4 va;
      const unsigned want = (unsigned)t;
      int guard = 0;
      for (;;) {
        asm volatile(
            "global_load_dwordx4 %0, %1, off sc0 sc1\n\t"
            "s_waitcnt vmcnt(0)"
            : "=&v"(va)
            : "v"(a0)
            : "memory");
        bool good = (va.x >> 16) == want && (va.y >> 16) == want &&
                    (va.z >> 16) == want && (va.w >> 16) == want;
        if (__all(good)) break;
        if (++guard > (1 << 16)) break;   // fail visibly, never hang the harness
      }
      // pack 4 h values into 2 half2 words -> ds_write_b64 (<=2-way alias, free)
      unsigned pk0 = (va.x & 0xffffu) | (va.y << 16);
      unsigned pk1 = (va.z & 0xffffu) | (va.w << 16);
      unsigned* dst = &hlds[(pidx >> 3) * 20 + (pidx & 7) * 2];
      dst[0] = pk0; dst[1] = pk1;
    }
    __syncthreads();

    // ---- h chunk (4x b128 broadcast reads) & 4-gate dot2 ----
    half2v hp[16];
    {
      const uintx4* hq = (const uintx4*)&hlds[cg * 20];
#pragma unroll
      for (int q = 0; q < 4; ++q) {
        uintx4 u = hq[q];
        hp[q * 4 + 0] = __builtin_bit_cast(half2v, u.x);
        hp[q * 4 + 1] = __builtin_bit_cast(half2v, u.y);
        hp[q * 4 + 2] = __builtin_bit_cast(half2v, u.z);
        hp[q * 4 + 3] = __builtin_bit_cast(half2v, u.w);
      }
    }
    float part[4] = {0.f, 0.f, 0.f, 0.f};
#pragma unroll
    for (int p = 0; p < 16; ++p) {
#pragma unroll
      for (int g = 0; g < 4; ++g)
        part[g] = __builtin_amdgcn_fdot2(wreg[g][p], hp[p], part[g], false);
    }
    // DPP xor-fold over the 16 cg lanes (full-rate VALU)
#pragma unroll
    for (int g = 0; g < 4; ++g) {
      part[g] = dpp_fold_add<0xB1>(part[g]);    // xor 1
      part[g] = dpp_fold_add<0x4E>(part[g]);    // xor 2
      part[g] = dpp_fold_add<0x141>(part[g]);   // xor 7 (row_half_mirror)
      part[g] = dpp_fold_add<0x140>(part[g]);   // xor 15 (row_mirror)
    }

    // ---- gate math (redundant across 16 lanes, zero divergence) ----
    float gi = part[0] + h2f(xg_cur.x);
    float gf = part[1] + h2f(xg_cur.y);
    float gg = part[2] + h2f(xg_cur.z);
    float go = part[3] + h2f(xg_cur.w);
    float i_ = 1.f / (1.f + __expf(-gi));
    float f_ = 1.f / (1.f + __expf(-gf));
    float ggc = fminf(fmaxf(gg, -15.f), 15.f);
    float e2 = __expf(-2.f * ggc);
    float g_ = (1.f - e2) / (1.f + e2);
    float o_ = 1.f / (1.f + __expf(-go));
    cst = f_ * cst + i_ * g_;
    float cc = fminf(fmaxf(cst, -15.f), 15.f);
    float e2c = __expf(-2.f * cc);
    float th = (1.f - e2c) / (1.f + e2c);
    float h_ = o_ * th;

    // ---- publish h_{t+1}: gather wave's 4 words -> one 16B store ----
    unsigned pw = (((unsigned)(t + 1)) << 16) | (unsigned)f2h_bits(h_);
    unsigned q1 = __shfl(pw, 16, 64);
    unsigned q2 = __shfl(pw, 32, 64);
    unsigned q3 = __shfl(pw, 48, 64);
    if (lane == 0) {
      uintx4 val;
      val.x = pw; val.y = q1; val.z = q2; val.w = q3;
      unsigned long long addr =
          (unsigned long long)(hbase + ((t + 1) & 1) * MEMD + w * 64 + wv * 4);
      asm volatile("global_store_dwordx4 %0, %1, off sc0 sc1"
                   :: "v"(addr), "v"(val) : "memory");
    }
    xg_cur = xg_next;
  }
}

// ---------- final reduction: out = exp(-sum |lh - rh|) ----------
__global__ __launch_bounds__(512) void finish_k(const unsigned* __restrict__ hbuf,
                                                float* __restrict__ out) {
  const int tid = threadIdx.x;   // epoch 2048 lives in the parity-0 buffers
  float l = h2f(hbuf[tid]);
  float r = h2f(hbuf[2 * MEMD + tid]);
  float d = fabsf(l - r);
#pragma unroll
  for (int m = 32; m >= 1; m >>= 1) d += __shfl_xor(d, m, 64);
  __shared__ float wsum[8];
  if ((tid & 63) == 0) wsum[tid >> 6] = d;
  __syncthreads();
  if (tid == 0) {
    float sum = 0.f;
#pragma unroll
    for (int i = 0; i < 8; ++i) sum += wsum[i];
    out[0] = expf(-sum);
  }
}

extern "C" void kernel_launch(void* const* d_in, const int* in_sizes, int n_in,
                              void* d_out, int out_size, void* d_ws, size_t ws_size,
                              hipStream_t stream) {
  const int*   lin  = (const int*)d_in[0];
  const int*   rin  = (const int*)d_in[1];
  const float* emb  = (const float*)d_in[2];
  const float* W_ih = (const float*)d_in[3];
  const float* W_hh = (const float*)d_in[4];
  const float* b_ih = (const float*)d_in[5];
  const float* b_hh = (const float*)d_in[6];
  float* out = (float*)d_out;

  unsigned char* ws = (unsigned char*)d_ws;
  unsigned short* xp = (unsigned short*)ws;
  unsigned* hbuf = (unsigned*)(ws + (size_t)2 * SEQL * G4 * sizeof(unsigned short));

  hipLaunchKernelGGL(init_k, dim3(2), dim3(1024), 0, stream, hbuf);
  hipLaunchKernelGGL(xp_gemm, dim3(SEQL / 64, G4 / 64, 2), dim3(256), 0, stream,
                     lin, rin, emb, W_ih, b_ih, b_hh, xp);
  hipLaunchKernelGGL(lstm_rec, dim3(2 * NWGS), dim3(1024), 0, stream, W_hh, xp, hbuf);
  hipLaunchKernelGGL(finish_k, dim3(1), dim3(512), 0, stream, hbuf, out);
}

// Round 10
// 3952.019 us; speedup vs baseline: 1.2724x; 1.2724x over previous
//
#include <hip/hip_runtime.h>
#include <hip/hip_bf16.h>

#define SEQL  2048
#define IND   256
#define MEMD  512
#define G4    2048   // 4*MEMD gate rows
#define NWG   16     // workgroups per sequence
#define VOCABN 100000

typedef __attribute__((ext_vector_type(4))) unsigned uintx4;
typedef __attribute__((ext_vector_type(2))) _Float16 half2v;

__device__ __forceinline__ unsigned short f2h_bits(float f) {
  _Float16 h = (_Float16)f;
  return __builtin_bit_cast(unsigned short, h);
}
__device__ __forceinline__ float h2f(unsigned bits) {
  return (float)__builtin_bit_cast(_Float16, (unsigned short)(bits & 0xffffu));
}

// DPP xor-fold add within 16-lane rows. CTRL: 0xB1=xor1, 0x4E=xor2,
// 0x141=row_half_mirror(xor7), 0x140=row_mirror(xor15).
template <int CTRL>
__device__ __forceinline__ float dpp_fold_add(float v) {
  int x = __builtin_amdgcn_update_dpp(0, __float_as_int(v), CTRL, 0xf, 0xf, true);
  return v + __int_as_float(x);
}

__device__ __forceinline__ bool chk8(const uintx4& a, const uintx4& b, unsigned want) {
  return (a.x >> 16) == want && (a.y >> 16) == want &&
         (a.z >> 16) == want && (a.w >> 16) == want &&
         (b.x >> 16) == want && (b.y >> 16) == want &&
         (b.z >> 16) == want && (b.w >> 16) == want;
}

// issue one probe: 2x dwordx4 (this lane's 8 h-words), agent scope
#define P_ISSUE(VA, VB, A0, A1)                                        \
  asm volatile("global_load_dwordx4 %0, %2, off sc0 sc1\n\t"           \
               "global_load_dwordx4 %1, %3, off sc0 sc1"               \
               : "=&v"(VA), "=&v"(VB) : "v"(A0), "v"(A1) : "memory")

// wait until the OLDEST outstanding probe (2 loads) is complete; tie regs so
// the compiler can't hoist the consuming checks above the wait (rule #18).
#define P_WAIT(VA, VB)                                                 \
  asm volatile("s_waitcnt vmcnt(2)" : "+v"(VA), "+v"(VB) :: "memory"); \
  __builtin_amdgcn_sched_barrier(0)

// ---------- init: zero the h publication buffer ----------
// hbuf layout: [seq][parity][512] u32 words, word = (epoch<<16) | f16(h)
__global__ void init_k(unsigned* __restrict__ hbuf) {
  int i = blockIdx.x * blockDim.x + threadIdx.x;
  if (i < 2 * 2 * MEMD) hbuf[i] = 0u;   // epoch 0, h = 0
}

// ---------- xp GEMM: xp[s][t][perm(n)] = emb[ids[t]] . W_ih[n] + b ----------
// Output layout per (s,t): pos = w*128 + hd*4 + gate  (ushort4 per (w,hd)), f16
__global__ __launch_bounds__(256) void xp_gemm(
    const int* __restrict__ lin, const int* __restrict__ rin,
    const float* __restrict__ emb, const float* __restrict__ W_ih,
    const float* __restrict__ b_ih, const float* __restrict__ b_hh,
    unsigned short* __restrict__ xp) {
  __shared__ float As[64][68];
  __shared__ float Bs[64][68];
  const int s = blockIdx.z;
  const int* ids = (s == 0) ? lin : rin;
  const int t0 = blockIdx.x * 64;
  const int n0 = blockIdx.y * 64;
  const int tid = threadIdx.x;
  const int tx = tid & 15, ty = tid >> 4;

  float acc[4][4];
#pragma unroll
  for (int i = 0; i < 4; ++i)
#pragma unroll
    for (int j = 0; j < 4; ++j) acc[i][j] = 0.f;

  for (int kc = 0; kc < IND; kc += 64) {
#pragma unroll
    for (int j = 0; j < 4; ++j) {
      int fi  = tid + 256 * j;       // 0..1023 float4 slots
      int row = fi >> 4;             // 0..63
      int c4  = fi & 15;             // float4 index within 64 k
      int id  = ids[t0 + row];
      id = max(0, min(id, VOCABN - 1));
      const float4 va = *(const float4*)(emb + (size_t)id * IND + kc + c4 * 4);
      As[c4 * 4 + 0][row] = va.x; As[c4 * 4 + 1][row] = va.y;
      As[c4 * 4 + 2][row] = va.z; As[c4 * 4 + 3][row] = va.w;
      const float4 vb = *(const float4*)(W_ih + (size_t)(n0 + row) * IND + kc + c4 * 4);
      Bs[c4 * 4 + 0][row] = vb.x; Bs[c4 * 4 + 1][row] = vb.y;
      Bs[c4 * 4 + 2][row] = vb.z; Bs[c4 * 4 + 3][row] = vb.w;
    }
    __syncthreads();
#pragma unroll 8
    for (int k = 0; k < 64; ++k) {
      const float4 a = *(const float4*)&As[k][tx * 4];
      const float4 b = *(const float4*)&Bs[k][ty * 4];
      acc[0][0] = fmaf(a.x, b.x, acc[0][0]); acc[0][1] = fmaf(a.x, b.y, acc[0][1]);
      acc[0][2] = fmaf(a.x, b.z, acc[0][2]); acc[0][3] = fmaf(a.x, b.w, acc[0][3]);
      acc[1][0] = fmaf(a.y, b.x, acc[1][0]); acc[1][1] = fmaf(a.y, b.y, acc[1][1]);
      acc[1][2] = fmaf(a.y, b.z, acc[1][2]); acc[1][3] = fmaf(a.y, b.w, acc[1][3]);
      acc[2][0] = fmaf(a.z, b.x, acc[2][0]); acc[2][1] = fmaf(a.z, b.y, acc[2][1]);
      acc[2][2] = fmaf(a.z, b.z, acc[2][2]); acc[2][3] = fmaf(a.z, b.w, acc[2][3]);
      acc[3][0] = fmaf(a.w, b.x, acc[3][0]); acc[3][1] = fmaf(a.w, b.y, acc[3][1]);
      acc[3][2] = fmaf(a.w, b.z, acc[3][2]); acc[3][3] = fmaf(a.w, b.w, acc[3][3]);
    }
    __syncthreads();
  }
#pragma unroll
  for (int ri = 0; ri < 4; ++ri) {
#pragma unroll
    for (int bj = 0; bj < 4; ++bj) {
      int t = t0 + tx * 4 + ri;
      int n = n0 + ty * 4 + bj;
      float v = acc[ri][bj] + b_ih[n] + b_hh[n];
      int w = (n & 511) >> 5;     // owning WG
      int gate = n >> 9;          // 0..3 (i,f,g,o)
      int hd = n & 31;            // local h dim
      int pos = w * 128 + hd * 4 + gate;
      xp[((size_t)s * SEQL + t) * G4 + pos] = f2h_bits(v);
    }
  }
}

// ---------- persistent recurrent kernel ----------
// 32 blocks x 512 threads. block -> (seq = blk&1, w = blk>>1).
// Gate-major: thread (cg=tid&15, rg=tid>>4) computes the 4 GATES of h-dim rg
// over k-chunk cg via v_dot2_f32_f16. DPP xor-fold -> all 16 lanes hold the
// 4 gate sums -> in-register gate math, single barrier.
// Wave 0 polls with a persistent 2-probe ring (counted vmcnt(2) waits):
// one probe in flight while the other is checked -> sampling at ~RT/2.
// Poll robustness: stale/under-waited register data can only FAIL the epoch
// check (epochs grow monotonically), and a probe's regs are reissued only
// after a wait that covered it (vmcnt FIFO) -> no WAW, no false positives.
// COHERENCE: all hbuf traffic is sc0 sc1 (agent) — anything less livelocks
// (R6 cross-XCD, R9 same-XCD both confirmed).
__global__ __launch_bounds__(512, 2) void lstm_rec(
    const float* __restrict__ W_hh,
    const unsigned short* __restrict__ xp,
    unsigned* __restrict__ hbuf) {
  __shared__ unsigned hlds[16 * 20];  // 16 chunks x 16 half2-words, stride 20
  const int blk = blockIdx.x;
  const int s = blk & 1;
  const int w = blk >> 1;          // 0..15
  const int tid = threadIdx.x;
  const int lane = tid & 63;
  const int wv = tid >> 6;         // wave id 0..7
  const int cg = tid & 15;         // k chunk group (32 k each)
  const int rg = tid >> 4;         // h dim owned (0..31); wave wv owns rgs 4wv..4wv+3

  // W slice, gate-major, f16-packed: wreg[g][p] = {W[row][cg*32+2p], W[row][cg*32+2p+1]}
  half2v wreg[4][16];
#pragma unroll
  for (int g = 0; g < 4; ++g) {
    const float* src = W_hh + ((size_t)g * MEMD + w * 32 + rg) * MEMD + cg * 32;
#pragma unroll
    for (int q = 0; q < 8; ++q) {
      const float4 v = *(const float4*)(src + q * 4);
      half2v p0; p0.x = (_Float16)v.x; p0.y = (_Float16)v.y;
      half2v p1; p1.x = (_Float16)v.z; p1.y = (_Float16)v.w;
      wreg[g][q * 2 + 0] = p0;
      wreg[g][q * 2 + 1] = p1;
    }
  }

  unsigned* hbase = hbuf + s * (2 * MEMD);
  // this thread's 4 gate biases: xp[s][t][w*128 + rg*4 + 0..3]
  const unsigned short* xq0 = xp + (size_t)s * SEQL * G4 + w * 128 + rg * 4;
  float cst = 0.f;                 // cell state for h-dim rg (redundant in 16 lanes)

  ushort4 xg_cur = *(const ushort4*)xq0;   // t = 0

  // probe ring registers (persist across steps)
  uintx4 pa0, pa1, pb0, pb1;
  if (wv == 0) {
    unsigned long long c0 = (unsigned long long)(hbase + 8 * lane);  // parity 0
    unsigned long long c1 = c0 + 16;
    P_ISSUE(pa0, pa1, c0, c1);
    P_ISSUE(pb0, pb1, c0, c1);
  }

  for (int t = 0; t < SEQL; ++t) {
    // prefetch next step's gate biases (independent of h -> hides latency)
    ushort4 xg_next;
    {
      int tn = (t + 1 < SEQL) ? t + 1 : t;
      xg_next = *(const ushort4*)(xq0 + (size_t)tn * G4);
    }

    // ---- wave0: poll h_t (epoch == t) via the 2-probe ring ----
    if (wv == 0) {
      const unsigned want = (unsigned)t;
      unsigned long long c0 =
          (unsigned long long)(hbase + (t & 1) * MEMD + 8 * lane);
      unsigned long long c1 = c0 + 16;
      uintx4 g0, g1;
      int guard = 0;
      for (;;) {
        P_WAIT(pa0, pa1);
        if (__all(chk8(pa0, pa1, want))) { g0 = pa0; g1 = pa1; break; }
        P_ISSUE(pa0, pa1, c0, c1);
        P_WAIT(pb0, pb1);
        if (__all(chk8(pb0, pb1, want))) { g0 = pb0; g1 = pb1; break; }
        P_ISSUE(pb0, pb1, c0, c1);
        if (++guard > (1 << 13)) { g0 = pa0; g1 = pa1; break; }  // fail visibly
      }
      // pack 8 h values into 4 half2 words; chunk = lane>>2, slot = (lane&3)*4
      uintx4 pk;
      pk.x = (g0.x & 0xffffu) | (g0.y << 16);
      pk.y = (g0.z & 0xffffu) | (g0.w << 16);
      pk.z = (g1.x & 0xffffu) | (g1.y << 16);
      pk.w = (g1.z & 0xffffu) | (g1.w << 16);
      *(uintx4*)&hlds[(lane >> 2) * 20 + (lane & 3) * 4] = pk;
    }
    __syncthreads();

    // ---- h chunk (4x b128, ~2-way alias -> cheap) & 4-gate dot2 ----
    half2v hp[16];
    {
      const uintx4* hq = (const uintx4*)&hlds[cg * 20];
#pragma unroll
      for (int q = 0; q < 4; ++q) {
        uintx4 u = hq[q];
        hp[q * 4 + 0] = __builtin_bit_cast(half2v, u.x);
        hp[q * 4 + 1] = __builtin_bit_cast(half2v, u.y);
        hp[q * 4 + 2] = __builtin_bit_cast(half2v, u.z);
        hp[q * 4 + 3] = __builtin_bit_cast(half2v, u.w);
      }
    }
    float part[4] = {0.f, 0.f, 0.f, 0.f};
#pragma unroll
    for (int p = 0; p < 16; ++p) {
#pragma unroll
      for (int g = 0; g < 4; ++g)
        part[g] = __builtin_amdgcn_fdot2(wreg[g][p], hp[p], part[g], false);
    }
    // DPP xor-fold over the 16 cg lanes (full-rate VALU)
#pragma unroll
    for (int g = 0; g < 4; ++g) {
      part[g] = dpp_fold_add<0xB1>(part[g]);    // xor 1
      part[g] = dpp_fold_add<0x4E>(part[g]);    // xor 2
      part[g] = dpp_fold_add<0x141>(part[g]);   // xor 7 (row_half_mirror)
      part[g] = dpp_fold_add<0x140>(part[g]);   // xor 15 (row_mirror)
    }

    // ---- gate math (redundant across 16 lanes, zero divergence) ----
    float gi = part[0] + h2f(xg_cur.x);
    float gf = part[1] + h2f(xg_cur.y);
    float gg = part[2] + h2f(xg_cur.z);
    float go = part[3] + h2f(xg_cur.w);
    float i_ = 1.f / (1.f + __expf(-gi));
    float f_ = 1.f / (1.f + __expf(-gf));
    float ggc = fminf(fmaxf(gg, -15.f), 15.f);
    float e2 = __expf(-2.f * ggc);
    float g_ = (1.f - e2) / (1.f + e2);
    float o_ = 1.f / (1.f + __expf(-go));
    cst = f_ * cst + i_ * g_;
    float cc = fminf(fmaxf(cst, -15.f), 15.f);
    float e2c = __expf(-2.f * cc);
    float th = (1.f - e2c) / (1.f + e2c);
    float h_ = o_ * th;

    // ---- publish h_{t+1}: gather wave's 4 words -> one 16B store ----
    unsigned pw = (((unsigned)(t + 1)) << 16) | (unsigned)f2h_bits(h_);
    unsigned q1 = __shfl(pw, 16, 64);
    unsigned q2 = __shfl(pw, 32, 64);
    unsigned q3 = __shfl(pw, 48, 64);
    if (lane == 0) {
      uintx4 val;
      val.x = pw; val.y = q1; val.z = q2; val.w = q3;
      unsigned long long addr =
          (unsigned long long)(hbase + ((t + 1) & 1) * MEMD + w * 32 + wv * 4);
      asm volatile("global_store_dwordx4 %0, %1, off sc0 sc1"
                   :: "v"(addr), "v"(val) : "memory");
    }
    xg_cur = xg_next;
  }
}

// ---------- final reduction: out = exp(-sum |lh - rh|) ----------
__global__ __launch_bounds__(512) void finish_k(const unsigned* __restrict__ hbuf,
                                                float* __restrict__ out) {
  const int tid = threadIdx.x;   // epoch 2048 lives in the parity-0 buffers
  float l = h2f(hbuf[tid]);
  float r = h2f(hbuf[2 * MEMD + tid]);
  float d = fabsf(l - r);
#pragma unroll
  for (int m = 32; m >= 1; m >>= 1) d += __shfl_xor(d, m, 64);
  __shared__ float wsum[8];
  if ((tid & 63) == 0) wsum[tid >> 6] = d;
  __syncthreads();
  if (tid == 0) {
    float sum = 0.f;
#pragma unroll
    for (int i = 0; i < 8; ++i) sum += wsum[i];
    out[0] = expf(-sum);
  }
}

extern "C" void kernel_launch(void* const* d_in, const int* in_sizes, int n_in,
                              void* d_out, int out_size, void* d_ws, size_t ws_size,
                              hipStream_t stream) {
  const int*   lin  = (const int*)d_in[0];
  const int*   rin  = (const int*)d_in[1];
  const float* emb  = (const float*)d_in[2];
  const float* W_ih = (const float*)d_in[3];
  const float* W_hh = (const float*)d_in[4];
  const float* b_ih = (const float*)d_in[5];
  const float* b_hh = (const float*)d_in[6];
  float* out = (float*)d_out;

  unsigned char* ws = (unsigned char*)d_ws;
  unsigned short* xp = (unsigned short*)ws;
  unsigned* hbuf = (unsigned*)(ws + (size_t)2 * SEQL * G4 * sizeof(unsigned short));

  hipLaunchKernelGGL(init_k, dim3(2), dim3(1024), 0, stream, hbuf);
  hipLaunchKernelGGL(xp_gemm, dim3(SEQL / 64, G4 / 64, 2), dim3(256), 0, stream,
                     lin, rin, emb, W_ih, b_ih, b_hh, xp);
  hipLaunchKernelGGL(lstm_rec, dim3(2 * NWG), dim3(512), 0, stream, W_hh, xp, hbuf);
  hipLaunchKernelGGL(finish_k, dim3(1), dim3(512), 0, stream, hbuf, out);
}

// Round 11
// 3435.100 us; speedup vs baseline: 1.4638x; 1.1505x over previous
//
#include <hip/hip_runtime.h>
#include <hip/hip_bf16.h>

#define SEQL  2048
#define IND   256
#define MEMD  512
#define G4    2048   // 4*MEMD gate rows
#define NWG   16     // workgroups per sequence
#define VOCABN 100000

// mailbox geometry (u32 words): [seq][consumer 0..15][parity][512]
#define MB_SEQ   (NWG * 2 * MEMD)   // 16384 words per sequence
#define MB_CONS  (2 * MEMD)         // 1024 words per consumer

typedef __attribute__((ext_vector_type(4))) unsigned uintx4;
typedef __attribute__((ext_vector_type(2))) _Float16 half2v;

__device__ __forceinline__ unsigned short f2h_bits(float f) {
  _Float16 h = (_Float16)f;
  return __builtin_bit_cast(unsigned short, h);
}
__device__ __forceinline__ float h2f(unsigned bits) {
  return (float)__builtin_bit_cast(_Float16, (unsigned short)(bits & 0xffffu));
}

// DPP xor-fold add within 16-lane rows. CTRL: 0xB1=xor1, 0x4E=xor2,
// 0x141=row_half_mirror(xor7), 0x140=row_mirror(xor15).
template <int CTRL>
__device__ __forceinline__ float dpp_fold_add(float v) {
  int x = __builtin_amdgcn_update_dpp(0, __float_as_int(v), CTRL, 0xf, 0xf, true);
  return v + __int_as_float(x);
}

// ---------- init: zero all mailboxes ----------
// word = (epoch<<16) | f16(h); epoch 0, h = 0
__global__ void init_k(unsigned* __restrict__ mb) {
  int i = blockIdx.x * blockDim.x + threadIdx.x;
  if (i < 2 * MB_SEQ) mb[i] = 0u;
}

// ---------- xp GEMM: xp[s][t][perm(n)] = emb[ids[t]] . W_ih[n] + b ----------
// Output layout per (s,t): pos = w*128 + hd*4 + gate  (ushort4 per (w,hd)), f16
__global__ __launch_bounds__(256) void xp_gemm(
    const int* __restrict__ lin, const int* __restrict__ rin,
    const float* __restrict__ emb, const float* __restrict__ W_ih,
    const float* __restrict__ b_ih, const float* __restrict__ b_hh,
    unsigned short* __restrict__ xp) {
  __shared__ float As[64][68];
  __shared__ float Bs[64][68];
  const int s = blockIdx.z;
  const int* ids = (s == 0) ? lin : rin;
  const int t0 = blockIdx.x * 64;
  const int n0 = blockIdx.y * 64;
  const int tid = threadIdx.x;
  const int tx = tid & 15, ty = tid >> 4;

  float acc[4][4];
#pragma unroll
  for (int i = 0; i < 4; ++i)
#pragma unroll
    for (int j = 0; j < 4; ++j) acc[i][j] = 0.f;

  for (int kc = 0; kc < IND; kc += 64) {
#pragma unroll
    for (int j = 0; j < 4; ++j) {
      int fi  = tid + 256 * j;       // 0..1023 float4 slots
      int row = fi >> 4;             // 0..63
      int c4  = fi & 15;             // float4 index within 64 k
      int id  = ids[t0 + row];
      id = max(0, min(id, VOCABN - 1));
      const float4 va = *(const float4*)(emb + (size_t)id * IND + kc + c4 * 4);
      As[c4 * 4 + 0][row] = va.x; As[c4 * 4 + 1][row] = va.y;
      As[c4 * 4 + 2][row] = va.z; As[c4 * 4 + 3][row] = va.w;
      const float4 vb = *(const float4*)(W_ih + (size_t)(n0 + row) * IND + kc + c4 * 4);
      Bs[c4 * 4 + 0][row] = vb.x; Bs[c4 * 4 + 1][row] = vb.y;
      Bs[c4 * 4 + 2][row] = vb.z; Bs[c4 * 4 + 3][row] = vb.w;
    }
    __syncthreads();
#pragma unroll 8
    for (int k = 0; k < 64; ++k) {
      const float4 a = *(const float4*)&As[k][tx * 4];
      const float4 b = *(const float4*)&Bs[k][ty * 4];
      acc[0][0] = fmaf(a.x, b.x, acc[0][0]); acc[0][1] = fmaf(a.x, b.y, acc[0][1]);
      acc[0][2] = fmaf(a.x, b.z, acc[0][2]); acc[0][3] = fmaf(a.x, b.w, acc[0][3]);
      acc[1][0] = fmaf(a.y, b.x, acc[1][0]); acc[1][1] = fmaf(a.y, b.y, acc[1][1]);
      acc[1][2] = fmaf(a.y, b.z, acc[1][2]); acc[1][3] = fmaf(a.y, b.w, acc[1][3]);
      acc[2][0] = fmaf(a.z, b.x, acc[2][0]); acc[2][1] = fmaf(a.z, b.y, acc[2][1]);
      acc[2][2] = fmaf(a.z, b.z, acc[2][2]); acc[2][3] = fmaf(a.z, b.w, acc[2][3]);
      acc[3][0] = fmaf(a.w, b.x, acc[3][0]); acc[3][1] = fmaf(a.w, b.y, acc[3][1]);
      acc[3][2] = fmaf(a.w, b.z, acc[3][2]); acc[3][3] = fmaf(a.w, b.w, acc[3][3]);
    }
    __syncthreads();
  }
#pragma unroll
  for (int ri = 0; ri < 4; ++ri) {
#pragma unroll
    for (int bj = 0; bj < 4; ++bj) {
      int t = t0 + tx * 4 + ri;
      int n = n0 + ty * 4 + bj;
      float v = acc[ri][bj] + b_ih[n] + b_hh[n];
      int w = (n & 511) >> 5;     // owning WG
      int gate = n >> 9;          // 0..3 (i,f,g,o)
      int hd = n & 31;            // local h dim
      int pos = w * 128 + hd * 4 + gate;
      xp[((size_t)s * SEQL + t) * G4 + pos] = f2h_bits(v);
    }
  }
}

// ---------- persistent recurrent kernel, per-consumer mailboxes ----------
// 32 blocks x 512 threads. block -> (seq = blk&1, w = blk>>1).
// Gate-major: thread (cg=tid&15, rg=tid>>4) computes the 4 GATES of h-dim rg
// over k-chunk cg via v_dot2_f32_f16; DPP xor-fold -> all 16 lanes hold the
// 4 gate sums -> in-register gate math, single barrier per step.
// EXCHANGE: publisher wave gathers its 4 packed words; lanes 0..15 store the
// 16B payload into 16 PRIVATE per-consumer mailboxes (fan-out-1 lines at the
// coherence point, vs 32-reader multicast on shared hbuf lines).
// Consumer wave0 polls only ITS 2KB mailbox (R7's serialized wait-all poll).
// COHERENCE: all mailbox traffic is sc0 sc1 (agent scope) — anything less
// livelocks (R6 cross-XCD, R9 same-XCD both confirmed on HW).
__global__ __launch_bounds__(512, 2) void lstm_rec(
    const float* __restrict__ W_hh,
    const unsigned short* __restrict__ xp,
    unsigned* __restrict__ mb) {
  __shared__ unsigned hlds[16 * 20];  // 16 chunks x 16 half2-words, stride 20
  const int blk = blockIdx.x;
  const int s = blk & 1;
  const int w = blk >> 1;          // 0..15
  const int tid = threadIdx.x;
  const int lane = tid & 63;
  const int wv = tid >> 6;         // wave id 0..7
  const int cg = tid & 15;         // k chunk group (32 k each)
  const int rg = tid >> 4;         // h dim owned (0..31); wave wv owns rgs 4wv..4wv+3

  // W slice, gate-major, f16-packed: wreg[g][p] = {W[row][cg*32+2p], W[row][cg*32+2p+1]}
  half2v wreg[4][16];
#pragma unroll
  for (int g = 0; g < 4; ++g) {
    const float* src = W_hh + ((size_t)g * MEMD + w * 32 + rg) * MEMD + cg * 32;
#pragma unroll
    for (int q = 0; q < 8; ++q) {
      const float4 v = *(const float4*)(src + q * 4);
      half2v p0; p0.x = (_Float16)v.x; p0.y = (_Float16)v.y;
      half2v p1; p1.x = (_Float16)v.z; p1.y = (_Float16)v.w;
      wreg[g][q * 2 + 0] = p0;
      wreg[g][q * 2 + 1] = p1;
    }
  }

  unsigned* mbs = mb + s * MB_SEQ;          // this sequence's mailboxes
  unsigned* mymb = mbs + w * MB_CONS;       // this WG's private mailbox
  // this thread's 4 gate biases: xp[s][t][w*128 + rg*4 + 0..3]
  const unsigned short* xq0 = xp + (size_t)s * SEQL * G4 + w * 128 + rg * 4;
  float cst = 0.f;                 // cell state for h-dim rg (redundant in 16 lanes)

  ushort4 xg_cur = *(const ushort4*)xq0;   // t = 0

  for (int t = 0; t < SEQL; ++t) {
    // prefetch next step's gate biases (independent of h -> hides latency)
    ushort4 xg_next;
    {
      int tn = (t + 1 < SEQL) ? t + 1 : t;
      xg_next = *(const ushort4*)(xq0 + (size_t)tn * G4);
    }

    // ---- wave0: poll h_t (epoch == t) from OUR mailbox; lane L owns 8L..8L+7 ----
    if (wv == 0) {
      const unsigned* hr = mymb + (t & 1) * MEMD + 8 * lane;
      unsigned long long a0 = (unsigned long long)hr;
      unsigned long long a1 = (unsigned long long)(hr + 4);
      uintx4 va, vb;
      const unsigned want = (unsigned)t;
      int guard = 0;
      for (;;) {
        asm volatile(
            "global_load_dwordx4 %0, %2, off sc0 sc1\n\t"
            "global_load_dwordx4 %1, %3, off sc0 sc1\n\t"
            "s_waitcnt vmcnt(0)"
            : "=&v"(va), "=&v"(vb)
            : "v"(a0), "v"(a1)
            : "memory");
        bool good = (va.x >> 16) == want && (va.y >> 16) == want &&
                    (va.z >> 16) == want && (va.w >> 16) == want &&
                    (vb.x >> 16) == want && (vb.y >> 16) == want &&
                    (vb.z >> 16) == want && (vb.w >> 16) == want;
        if (__all(good)) break;
        if (++guard > (1 << 16)) break;   // fail visibly, never hang the harness
      }
      // pack 8 h values into 4 half2 words; chunk = lane>>2, slot = (lane&3)*4
      uintx4 pk;
      pk.x = (va.x & 0xffffu) | (va.y << 16);
      pk.y = (va.z & 0xffffu) | (va.w << 16);
      pk.z = (vb.x & 0xffffu) | (vb.y << 16);
      pk.w = (vb.z & 0xffffu) | (vb.w << 16);
      *(uintx4*)&hlds[(lane >> 2) * 20 + (lane & 3) * 4] = pk;
    }
    __syncthreads();

    // ---- h chunk (4x b128, ~2-way alias -> cheap) & 4-gate dot2 ----
    half2v hp[16];
    {
      const uintx4* hq = (const uintx4*)&hlds[cg * 20];
#pragma unroll
      for (int q = 0; q < 4; ++q) {
        uintx4 u = hq[q];
        hp[q * 4 + 0] = __builtin_bit_cast(half2v, u.x);
        hp[q * 4 + 1] = __builtin_bit_cast(half2v, u.y);
        hp[q * 4 + 2] = __builtin_bit_cast(half2v, u.z);
        hp[q * 4 + 3] = __builtin_bit_cast(half2v, u.w);
      }
    }
    float part[4] = {0.f, 0.f, 0.f, 0.f};
#pragma unroll
    for (int p = 0; p < 16; ++p) {
#pragma unroll
      for (int g = 0; g < 4; ++g)
        part[g] = __builtin_amdgcn_fdot2(wreg[g][p], hp[p], part[g], false);
    }
    // DPP xor-fold over the 16 cg lanes (full-rate VALU)
#pragma unroll
    for (int g = 0; g < 4; ++g) {
      part[g] = dpp_fold_add<0xB1>(part[g]);    // xor 1
      part[g] = dpp_fold_add<0x4E>(part[g]);    // xor 2
      part[g] = dpp_fold_add<0x141>(part[g]);   // xor 7 (row_half_mirror)
      part[g] = dpp_fold_add<0x140>(part[g]);   // xor 15 (row_mirror)
    }

    // ---- gate math (redundant across 16 lanes, zero divergence) ----
    float gi = part[0] + h2f(xg_cur.x);
    float gf = part[1] + h2f(xg_cur.y);
    float gg = part[2] + h2f(xg_cur.z);
    float go = part[3] + h2f(xg_cur.w);
    float i_ = 1.f / (1.f + __expf(-gi));
    float f_ = 1.f / (1.f + __expf(-gf));
    float ggc = fminf(fmaxf(gg, -15.f), 15.f);
    float e2 = __expf(-2.f * ggc);
    float g_ = (1.f - e2) / (1.f + e2);
    float o_ = 1.f / (1.f + __expf(-go));
    cst = f_ * cst + i_ * g_;
    float cc = fminf(fmaxf(cst, -15.f), 15.f);
    float e2c = __expf(-2.f * cc);
    float th = (1.f - e2c) / (1.f + e2c);
    float h_ = o_ * th;

    // ---- publish h_{t+1}: 16B payload -> 16 private mailboxes (lanes 0..15) ----
    unsigned pw = (((unsigned)(t + 1)) << 16) | (unsigned)f2h_bits(h_);
    unsigned q1 = __shfl(pw, 16, 64);   // broadcast to all lanes
    unsigned q2 = __shfl(pw, 32, 64);
    unsigned q3 = __shfl(pw, 48, 64);
    if (lane < 16) {
      uintx4 val;
      val.x = pw; val.y = q1; val.z = q2; val.w = q3;
      unsigned long long addr = (unsigned long long)(
          mbs + lane * MB_CONS + ((t + 1) & 1) * MEMD + w * 32 + wv * 4);
      asm volatile("global_store_dwordx4 %0, %1, off sc0 sc1"
                   :: "v"(addr), "v"(val) : "memory");
    }
    xg_cur = xg_next;
  }
}

// ---------- final reduction: out = exp(-sum |lh - rh|) ----------
// epoch 2048 (even) lives in parity-0; read consumer 0's mailbox of each seq.
__global__ __launch_bounds__(512) void finish_k(const unsigned* __restrict__ mb,
                                                float* __restrict__ out) {
  const int tid = threadIdx.x;
  float l = h2f(mb[tid]);
  float r = h2f(mb[MB_SEQ + tid]);
  float d = fabsf(l - r);
#pragma unroll
  for (int m = 32; m >= 1; m >>= 1) d += __shfl_xor(d, m, 64);
  __shared__ float wsum[8];
  if ((tid & 63) == 0) wsum[tid >> 6] = d;
  __syncthreads();
  if (tid == 0) {
    float sum = 0.f;
#pragma unroll
    for (int i = 0; i < 8; ++i) sum += wsum[i];
    out[0] = expf(-sum);
  }
}

extern "C" void kernel_launch(void* const* d_in, const int* in_sizes, int n_in,
                              void* d_out, int out_size, void* d_ws, size_t ws_size,
                              hipStream_t stream) {
  const int*   lin  = (const int*)d_in[0];
  const int*   rin  = (const int*)d_in[1];
  const float* emb  = (const float*)d_in[2];
  const float* W_ih = (const float*)d_in[3];
  const float* W_hh = (const float*)d_in[4];
  const float* b_ih = (const float*)d_in[5];
  const float* b_hh = (const float*)d_in[6];
  float* out = (float*)d_out;

  unsigned char* ws = (unsigned char*)d_ws;
  unsigned short* xp = (unsigned short*)ws;
  unsigned* mb = (unsigned*)(ws + (size_t)2 * SEQL * G4 * sizeof(unsigned short));

  hipLaunchKernelGGL(init_k, dim3(2 * MB_SEQ / 1024), dim3(1024), 0, stream, mb);
  hipLaunchKernelGGL(xp_gemm, dim3(SEQL / 64, G4 / 64, 2), dim3(256), 0, stream,
                     lin, rin, emb, W_ih, b_ih, b_hh, xp);
  hipLaunchKernelGGL(lstm_rec, dim3(2 * NWG), dim3(512), 0, stream, W_hh, xp, mb);
  hipLaunchKernelGGL(finish_k, dim3(1), dim3(512), 0, stream, mb, out);
}